// Round 6
// baseline (389.112 us; speedup 1.0000x reference)
//
#include <hip/hip_runtime.h>

#define NB 8
#define NTQ 1024
#define NTM 1024
#define ND 512
#define NATTN 512
#define NH 8
#define NDH 64

typedef _Float16 half8 __attribute__((ext_vector_type(8)));
typedef float f32x4 __attribute__((ext_vector_type(4)));

// ---------------------------------------------------------------------------
// One-shot W transpose+convert: Wt[z][n][k] (fp16) = W_z[k][n] (fp32).
// ---------------------------------------------------------------------------
__global__ __launch_bounds__(256) void wprep_kernel(
    const float* __restrict__ Wq, const float* __restrict__ Wk,
    const float* __restrict__ Wv, _Float16* __restrict__ Wt) {
  const int z = blockIdx.z;
  const float* __restrict__ W = (z == 0) ? Wq : ((z == 1) ? Wk : Wv);
  _Float16* __restrict__ out = Wt + (size_t)z * NATTN * ND;
  const int k0 = blockIdx.x * 64;
  const int n0 = blockIdx.y * 64;
  __shared__ __align__(16) _Float16 Ls[64][72];
  const int t = threadIdx.x;
  const int sr = t >> 2, sc = (t & 3) * 16;
  const float4* src = (const float4*)(W + (size_t)(k0 + sr) * NATTN + n0 + sc);
  float4 f0 = src[0], f1 = src[1], f2 = src[2], f3 = src[3];
  float gv[16];
  *(float4*)&gv[0] = f0; *(float4*)&gv[4] = f1;
  *(float4*)&gv[8] = f2; *(float4*)&gv[12] = f3;
#pragma unroll
  for (int j = 0; j < 16; j++) Ls[sc + j][sr] = (_Float16)gv[j];
  __syncthreads();
  _Float16* dst = out + (size_t)(n0 + sr) * ND + k0 + sc;
  *(half8*)dst = *(const half8*)&Ls[sr][sc];
  *(half8*)(dst + 8) = *(const half8*)&Ls[sr][sc + 8];
}

// ---------------------------------------------------------------------------
// Projection: out = A @ W, tile 128 rows x 128 cols, BK=64 (was 64x128).
// 32 MFMA per wave per barrier pair (2x round-4), A staged once per 128 rows.
// grid = 768, XCD-pinned: all 4 col-tiles of a row-panel (and z=1/z=2's
// shared memory panels) on one XCD -> A tile L2-resident.
// Epilogues bounce through LDS for contiguous 128B/thread half8 stores.
// ---------------------------------------------------------------------------
__global__ __launch_bounds__(256) void proj_kernel(
    const float* __restrict__ inputs, const float* __restrict__ memory,
    const _Float16* __restrict__ Wt, _Float16* __restrict__ Qh,
    _Float16* __restrict__ Kh, _Float16* __restrict__ Vth) {
  const int id = blockIdx.x;  // 0..767
  const int xcd = id & 7;
  const int g = id >> 3;      // 0..95
  const int z = g >> 5;       // 0..2
  const int gg = g & 31;      // 0..31
  const int row0 = (xcd * 8 + (gg >> 2)) * 128;  // 0..8064
  const int col0 = (gg & 3) * 128;               // 0,128,256,384

  const float* __restrict__ A = (z == 0) ? inputs : memory;
  const _Float16* __restrict__ Wz = Wt + (size_t)z * NATTN * ND;

  __shared__ __align__(16) _Float16 pool[128 * 72 + 128 * 72];  // 36 KB
  _Float16* Asb = pool;              // [128][72] A tile (fp16)
  _Float16* Wsb = pool + 128 * 72;   // [128][72] W tile [n][k]

  const int t = threadIdx.x;
  const int w = t >> 6, L = t & 63;
  const int lrow = L & 15, quad = L >> 4;
  const int ar = t >> 1;         // 0..127 (staging row)
  const int ac = (t & 1) * 32;   // 0 or 32 (staging k-offset)

  const f32x4 zf = {0.f, 0.f, 0.f, 0.f};
  f32x4 acc0[8], acc1[8];
#pragma unroll
  for (int i = 0; i < 8; i++) { acc0[i] = zf; acc1[i] = zf; }

  for (int k0 = 0; k0 < ND; k0 += 64) {
    {  // stage A fp32 -> fp16: one row per thread-pair, 32 floats each
      const float4* src = (const float4*)(A + (size_t)(row0 + ar) * ND + k0 + ac);
#pragma unroll
      for (int j = 0; j < 4; j++) {
        float4 fa = src[2 * j], fb = src[2 * j + 1];
        half8 h;
        h[0] = (_Float16)fa.x; h[1] = (_Float16)fa.y;
        h[2] = (_Float16)fa.z; h[3] = (_Float16)fa.w;
        h[4] = (_Float16)fb.x; h[5] = (_Float16)fb.y;
        h[6] = (_Float16)fb.z; h[7] = (_Float16)fb.w;
        *(half8*)&Asb[ar * 72 + ac + 8 * j] = h;
      }
    }
    {  // stage W tile: coalesced half8 copy of Wt rows (n-major, k-contig)
      const half8* wsrc = (const half8*)(Wz + (size_t)(col0 + ar) * ND + k0 + ac);
#pragma unroll
      for (int j = 0; j < 4; j++) *(half8*)&Wsb[ar * 72 + ac + 8 * j] = wsrc[j];
    }
    __syncthreads();
#pragma unroll
    for (int ks = 0; ks < 2; ks++) {
      half8 a0 = *(const half8*)&Asb[(w * 32 + lrow) * 72 + ks * 32 + quad * 8];
      half8 a1 = *(const half8*)&Asb[(w * 32 + 16 + lrow) * 72 + ks * 32 + quad * 8];
#pragma unroll
      for (int nt = 0; nt < 8; nt++) {
        half8 b = *(const half8*)&Wsb[(nt * 16 + lrow) * 72 + ks * 32 + quad * 8];
        acc0[nt] = __builtin_amdgcn_mfma_f32_16x16x32_f16(a0, b, acc0[nt], 0, 0, 0);
        acc1[nt] = __builtin_amdgcn_mfma_f32_16x16x32_f16(a1, b, acc1[nt], 0, 0, 0);
      }
    }
    __syncthreads();
  }

  const int bb = row0 >> 10;
  const int tr0 = row0 & 1023;
  const int hh0 = col0 >> 6;  // even

  if (z <= 1) {
    // bounce via pool reused as [128][136] for contiguous half8 stores
#pragma unroll
    for (int nt = 0; nt < 8; nt++)
#pragma unroll
      for (int r = 0; r < 4; r++) {
        pool[(w * 32 + quad * 4 + r) * 136 + nt * 16 + lrow] = (_Float16)acc0[nt][r];
        pool[(w * 32 + 16 + quad * 4 + r) * 136 + nt * 16 + lrow] = (_Float16)acc1[nt][r];
      }
    __syncthreads();
    const int er = t >> 1;   // 0..127 output row
    const int eh = t & 1;    // head offset within the 2-head col tile
    _Float16* base = (z == 0) ? Qh : Kh;
    _Float16* dst = base + (size_t)(bb * NH + hh0 + eh) * NTQ * NDH +
                    (size_t)(tr0 + er) * NDH;
#pragma unroll
    for (int j = 0; j < 8; j++)
      *(half8*)(dst + 8 * j) = *(const half8*)&pool[er * 136 + eh * 64 + 8 * j];
  } else {
    // V: bounce transposed via pool as [128 cols][136] -> Vth[b][h][d][m]
#pragma unroll
    for (int nt = 0; nt < 8; nt++)
#pragma unroll
      for (int r = 0; r < 4; r++) {
        pool[(nt * 16 + lrow) * 136 + w * 32 + quad * 4 + r] = (_Float16)acc0[nt][r];
        pool[(nt * 16 + lrow) * 136 + w * 32 + 16 + quad * 4 + r] = (_Float16)acc1[nt][r];
      }
    __syncthreads();
    const int ec = t >> 1;         // 0..127 col (d across 2 heads)
    const int em = (t & 1) * 64;   // m offset
    _Float16* dst = Vth +
        ((size_t)(bb * NH + hh0 + (ec >> 6)) * NDH + (ec & 63)) * NTM + tr0 + em;
#pragma unroll
    for (int j = 0; j < 8; j++)
      *(half8*)(dst + 8 * j) = *(const half8*)&pool[ec * 136 + em + 8 * j];
  }
}

// ---------------------------------------------------------------------------
// Attention — byte-identical to round 4 (best verified attn).
// ---------------------------------------------------------------------------
__global__ __launch_bounds__(256) void attn_kernel(
    const _Float16* __restrict__ Qh, const _Float16* __restrict__ Kh,
    const _Float16* __restrict__ Vth, const int* __restrict__ mem_len,
    const int* __restrict__ qry_len, float* __restrict__ ctx_out,
    float* __restrict__ align_out) {
  const int bh = blockIdx.x;  // 0..63
  const int qt = blockIdx.y;  // 0..15
  const int bb = bh >> 3;
  const int hh = bh & 7;
  const int q0 = qt * 64;

  __shared__ __align__(16) _Float16 Ks[64][72];
  __shared__ __align__(16) _Float16 Vts[64][72];   // [d][m_local]
  __shared__ __align__(16) _Float16 Ps[4][16][72]; // per-wave P (A-layout src)
  __shared__ float vsum_lds[64];

  const int t = threadIdx.x, w = t >> 6, L = t & 63;
  const int lrow = L & 15, quad = L >> 4;
  const int qlen = qry_len[bb], mlen = mem_len[bb];
  const int mtop = (mlen + 63) >> 6;
  const bool has_causal = q0 < qlen;          // block-uniform
  const bool has_uniform = (q0 + 64) > qlen;  // block-uniform
  const int n_comp = has_causal ? min(qt + 1, mtop) : 0;
  const _Float16* Qbase = Qh + (size_t)bh * NTQ * NDH;
  const _Float16* Kbase = Kh + (size_t)bh * NTM * NDH;
  const _Float16* Vbase = Vth + (size_t)bh * NDH * NTM;
  const int sr = t >> 2, sc = (t & 3) * 16;
  const f32x4 zf = {0.f, 0.f, 0.f, 0.f};
  float* abase = align_out + (size_t)bh * NTQ * NTM;
  float* cbase = ctx_out + (size_t)bb * NTQ * NATTN + (size_t)hh * NDH;

  if (has_causal) {
    // ---- zero-fill skipped alignment columns for causal rows only ----
    if (n_comp < 16) {
      const int c0 = n_comp * 64;
      const int row = q0 + sr;
      if (row < qlen) {
        float* rp = abase + (size_t)row * NTM;
        const float4 z4 = {0.f, 0.f, 0.f, 0.f};
        for (int c = c0 + (t & 3) * 4; c < NTM; c += 16) *(float4*)(rp + c) = z4;
      }
    }
    // ---- Q fragments in registers (wave-private rows) ----
    const int qrow = q0 + w * 16 + lrow;
    const half8 qa0 = *(const half8*)(Qbase + (size_t)qrow * NDH + quad * 8);
    const half8 qa1 = *(const half8*)(Qbase + (size_t)qrow * NDH + 32 + quad * 8);
    const int qg = q0 + w * 16 + quad * 4;  // + r = global q row
    float rowsum[4] = {0.f, 0.f, 0.f, 0.f};

    // ---- pass 1: denominators (prefetched K staging) ----
    half8 kr0, kr1;
    {
      const half8* src = (const half8*)(Kbase + (size_t)sr * NDH + sc);
      kr0 = src[0]; kr1 = src[1];
    }
    for (int mt = 0; mt < n_comp; mt++) {
      *(half8*)&Ks[sr][sc] = kr0;
      *(half8*)&Ks[sr][sc + 8] = kr1;
      __syncthreads();
      if (mt + 1 < n_comp) {  // issue-early: overlaps the compute below
        const half8* src =
            (const half8*)(Kbase + (size_t)((mt + 1) * 64 + sr) * NDH + sc);
        kr0 = src[0]; kr1 = src[1];
      }
      f32x4 sacc[4];
#pragma unroll
      for (int i = 0; i < 4; i++) sacc[i] = zf;
#pragma unroll
      for (int nt = 0; nt < 4; nt++) {
        half8 b0 = *(const half8*)&Ks[nt * 16 + lrow][quad * 8];
        half8 b1 = *(const half8*)&Ks[nt * 16 + lrow][32 + quad * 8];
        sacc[nt] = __builtin_amdgcn_mfma_f32_16x16x32_f16(qa0, b0, sacc[nt], 0, 0, 0);
        sacc[nt] = __builtin_amdgcn_mfma_f32_16x16x32_f16(qa1, b1, sacc[nt], 0, 0, 0);
      }
#pragma unroll
      for (int nt = 0; nt < 4; nt++) {
        int m = mt * 64 + nt * 16 + lrow;
#pragma unroll
        for (int r = 0; r < 4; r++) {
          int q = qg + r;
          float p;
          if (q >= qlen) p = 0.0f;               // uniform row: handled later
          else if (m > q || m >= mlen) p = 0.0f; // masked
          else p = __expf(sacc[nt][r] * 0.125f);
          rowsum[r] += p;
        }
      }
      __syncthreads();
    }
    float inv[4];
#pragma unroll
    for (int r = 0; r < 4; r++) {
      float s = rowsum[r];
      s += __shfl_xor(s, 1, 16);
      s += __shfl_xor(s, 2, 16);
      s += __shfl_xor(s, 4, 16);
      s += __shfl_xor(s, 8, 16);
      inv[r] = 1.0f / s;  // inf for uniform rows; never used
    }

    // ---- pass 2: alignments + contexts (prefetched K+V staging) ----
    f32x4 cacc[4];
#pragma unroll
    for (int i = 0; i < 4; i++) cacc[i] = zf;

    half8 vr0, vr1;
    {
      const half8* ksrc = (const half8*)(Kbase + (size_t)sr * NDH + sc);
      kr0 = ksrc[0]; kr1 = ksrc[1];
      const half8* vsrc = (const half8*)(Vbase + (size_t)sr * NTM + sc);
      vr0 = vsrc[0]; vr1 = vsrc[1];
    }
    for (int mt = 0; mt < n_comp; mt++) {
      *(half8*)&Ks[sr][sc] = kr0;
      *(half8*)&Ks[sr][sc + 8] = kr1;
      *(half8*)&Vts[sr][sc] = vr0;
      *(half8*)&Vts[sr][sc + 8] = vr1;
      __syncthreads();
      if (mt + 1 < n_comp) {  // issue-early: overlaps the compute below
        const half8* ksrc =
            (const half8*)(Kbase + (size_t)((mt + 1) * 64 + sr) * NDH + sc);
        kr0 = ksrc[0]; kr1 = ksrc[1];
        const half8* vsrc =
            (const half8*)(Vbase + (size_t)sr * NTM + (mt + 1) * 64 + sc);
        vr0 = vsrc[0]; vr1 = vsrc[1];
      }
      f32x4 sacc[4];
#pragma unroll
      for (int i = 0; i < 4; i++) sacc[i] = zf;
#pragma unroll
      for (int nt = 0; nt < 4; nt++) {
        half8 b0 = *(const half8*)&Ks[nt * 16 + lrow][quad * 8];
        half8 b1 = *(const half8*)&Ks[nt * 16 + lrow][32 + quad * 8];
        sacc[nt] = __builtin_amdgcn_mfma_f32_16x16x32_f16(qa0, b0, sacc[nt], 0, 0, 0);
        sacc[nt] = __builtin_amdgcn_mfma_f32_16x16x32_f16(qa1, b1, sacc[nt], 0, 0, 0);
      }
#pragma unroll
      for (int nt = 0; nt < 4; nt++) {
        int m = mt * 64 + nt * 16 + lrow;
#pragma unroll
        for (int r = 0; r < 4; r++) {
          int q = qg + r;
          float p;
          if (q >= qlen) p = 0.0f;               // uniform row: handled later
          else if (m > q || m >= mlen) p = 0.0f;
          else p = __expf(sacc[nt][r] * 0.125f) * inv[r];
          if (q < qlen) abase[(size_t)q * NTM + m] = p;
          Ps[w][quad * 4 + r][nt * 16 + lrow] = (_Float16)p;
        }
      }
      // P @ V  (Ps is per-wave; in-wave DS ordering suffices, no barrier)
#pragma unroll
      for (int ks = 0; ks < 2; ks++) {
        half8 a = *(const half8*)&Ps[w][lrow][ks * 32 + quad * 8];
#pragma unroll
        for (int dt = 0; dt < 4; dt++) {
          half8 b = *(const half8*)&Vts[dt * 16 + lrow][ks * 32 + quad * 8];
          cacc[dt] = __builtin_amdgcn_mfma_f32_16x16x32_f16(a, b, cacc[dt], 0, 0, 0);
        }
      }
      __syncthreads();
    }

#pragma unroll
    for (int dt = 0; dt < 4; dt++) {
#pragma unroll
      for (int r = 0; r < 4; r++) {
        int q = qg + r;
        if (q < qlen) cbase[(size_t)q * NATTN + dt * 16 + lrow] = cacc[dt][r];
      }
    }
  }

  // ---- uniform rows: alignments = 1/1024 exactly; ctx = mean of V ----
  if (has_uniform) {
    const int d = t >> 2;   // 0..63
    const int seg = t & 3;  // 256-col segment
    const _Float16* vp = Vbase + (size_t)d * NTM + seg * 256;
    float s = 0.f;
#pragma unroll
    for (int j = 0; j < 32; j++) {
      half8 v = *(const half8*)(vp + 8 * j);
#pragma unroll
      for (int e = 0; e < 8; e++) s += (float)v[e];
    }
    s += __shfl_xor(s, 1, 4);
    s += __shfl_xor(s, 2, 4);
    if (seg == 0) vsum_lds[d] = s * (1.0f / 1024.0f);
    __syncthreads();
    const int qu0 = (q0 > qlen) ? q0 : qlen;
    for (int q = qu0 + w; q < q0 + 64; q += 4)
      cbase[(size_t)q * NATTN + L] = vsum_lds[L];
    const float cval = 1.0f / 1024.0f;  // exact (2^-10), matches ref softmax
    const f32x4 c4 = {cval, cval, cval, cval};
    for (int q = qu0 + w; q < q0 + 64; q += 4) {
      float* rp = abase + (size_t)q * NTM + L * 4;
#pragma unroll
      for (int j = 0; j < 4; j++) *(f32x4*)(rp + j * 256) = c4;
    }
  }
}

extern "C" void kernel_launch(void* const* d_in, const int* in_sizes, int n_in,
                              void* d_out, int out_size, void* d_ws,
                              size_t ws_size, hipStream_t stream) {
  const float* inputs = (const float*)d_in[0];
  const float* memory = (const float*)d_in[1];
  const float* Wq = (const float*)d_in[2];
  const float* Wk = (const float*)d_in[3];
  const float* Wv = (const float*)d_in[4];
  const int* mlen = (const int*)d_in[5];
  const int* qlen = (const int*)d_in[6];

  float* ctx = (float*)d_out;                     // (B,TQ,ATTN)
  float* align = ctx + (size_t)NB * NTQ * NATTN;  // (B,H,TQ,TM)

  _Float16* Qh = (_Float16*)d_ws;                    // 8 MB
  _Float16* Kh = Qh + (size_t)NB * NH * NTQ * NDH;   // 8 MB
  _Float16* Vth = Kh + (size_t)NB * NH * NTM * NDH;  // 8 MB
  // Wt (1.5 MB fp16) parked at the head of the alignments buffer: read only
  // by proj_kernel, fully overwritten by attn_kernel later in stream order.
  _Float16* Wt = (_Float16*)align;

  wprep_kernel<<<dim3(8, 8, 3), 256, 0, stream>>>(Wq, Wk, Wv, Wt);
  proj_kernel<<<dim3(768), 256, 0, stream>>>(inputs, memory, Wt, Qh, Kh, Vth);
  attn_kernel<<<dim3(64, 16), 256, 0, stream>>>(Qh, Kh, Vth, mlen, qlen, ctx,
                                                align);
}

// Round 7
// 376.101 us; speedup vs baseline: 1.0346x; 1.0346x over previous
//
#include <hip/hip_runtime.h>

#define NB 8
#define NTQ 1024
#define NTM 1024
#define ND 512
#define NATTN 512
#define NH 8
#define NDH 64

typedef _Float16 half8 __attribute__((ext_vector_type(8)));
typedef float f32x4 __attribute__((ext_vector_type(4)));

// ---------------------------------------------------------------------------
// One-shot W transpose+convert: Wt[z][n][k] (fp16) = W_z[k][n] (fp32).
// ---------------------------------------------------------------------------
__global__ __launch_bounds__(256) void wprep_kernel(
    const float* __restrict__ Wq, const float* __restrict__ Wk,
    const float* __restrict__ Wv, _Float16* __restrict__ Wt) {
  const int z = blockIdx.z;
  const float* __restrict__ W = (z == 0) ? Wq : ((z == 1) ? Wk : Wv);
  _Float16* __restrict__ out = Wt + (size_t)z * NATTN * ND;
  const int k0 = blockIdx.x * 64;
  const int n0 = blockIdx.y * 64;
  __shared__ __align__(16) _Float16 Ls[64][72];
  const int t = threadIdx.x;
  const int sr = t >> 2, sc = (t & 3) * 16;
  const float4* src = (const float4*)(W + (size_t)(k0 + sr) * NATTN + n0 + sc);
  float4 f0 = src[0], f1 = src[1], f2 = src[2], f3 = src[3];
  float gv[16];
  *(float4*)&gv[0] = f0; *(float4*)&gv[4] = f1;
  *(float4*)&gv[8] = f2; *(float4*)&gv[12] = f3;
#pragma unroll
  for (int j = 0; j < 16; j++) Ls[sc + j][sr] = (_Float16)gv[j];
  __syncthreads();
  _Float16* dst = out + (size_t)(n0 + sr) * ND + k0 + sc;
  *(half8*)dst = *(const half8*)&Ls[sr][sc];
  *(half8*)(dst + 8) = *(const half8*)&Ls[sr][sc + 8];
}

// ---------------------------------------------------------------------------
// Projection: out = A @ W, tiles 64 rows x 128 cols, BK=64 (round-4 proven
// structure, reverted from the 128x128 regression). Two additions:
//   (a) early-exit for Q blocks with rows >= qlen / K blocks with rows >=
//       mlen — attn provably never reads them (uniform rows bypass Q; K
//       tiles beyond mtop-1 untouched; V needed everywhere, no skip).
//   (b) issue-early register prefetch of next k-step A/W (T14): load flight
//       overlaps the 16-MFMA compute instead of the loop-head stall.
// ---------------------------------------------------------------------------
__global__ __launch_bounds__(256) void proj_kernel(
    const float* __restrict__ inputs, const float* __restrict__ memory,
    const _Float16* __restrict__ Wt, const int* __restrict__ mem_len,
    const int* __restrict__ qry_len, _Float16* __restrict__ Qh,
    _Float16* __restrict__ Kh, _Float16* __restrict__ Vth) {
  const int id = blockIdx.x;        // 0..1535
  const int xcd = id & 7;
  const int g = id >> 3;            // 0..191
  const int z = g >> 6;             // 0..2
  const int gg = g & 63;
  const int row0 = (xcd * 16 + (gg >> 2)) * 64;  // 0..8128
  const int col0 = (gg & 3) * 128;               // 0,128,256,384

  // (a) dead-projection early-exit (block-uniform, before any barrier)
  const int bb = row0 >> 10;
  const int r_in_b = row0 & 1023;
  if (z == 0 && r_in_b >= qry_len[bb]) return;
  if (z == 1 && r_in_b >= mem_len[bb]) return;

  const float* __restrict__ A = (z == 0) ? inputs : memory;
  const _Float16* __restrict__ Wz = Wt + (size_t)z * NATTN * ND;

  __shared__ __align__(16) _Float16 pool[64 * 72 + 128 * 72];
  _Float16* Asb = pool;             // [64][72]  A tile (fp16)
  _Float16* Wsb = pool + 64 * 72;   // [128][72] W tile [n][k]

  const int t = threadIdx.x;
  const int w = t >> 6, L = t & 63;
  const int lrow = L & 15, quad = L >> 4;
  const int sr = t >> 2, sc = (t & 3) * 16;
  const int sr2 = t >> 1, sc2 = (t & 1) * 32;

  const f32x4 zf = {0.f, 0.f, 0.f, 0.f};
  f32x4 acc[8];
#pragma unroll
  for (int i = 0; i < 8; i++) acc[i] = zf;

  // (b) preload k-step 0 into registers
  float4 pf0, pf1, pf2, pf3;
  half8 pw0, pw1, pw2, pw3;
  {
    const float4* src = (const float4*)(A + (size_t)(row0 + sr) * ND + sc);
    pf0 = src[0]; pf1 = src[1]; pf2 = src[2]; pf3 = src[3];
    const half8* wsrc = (const half8*)(Wz + (size_t)(col0 + sr2) * ND + sc2);
    pw0 = wsrc[0]; pw1 = wsrc[1]; pw2 = wsrc[2]; pw3 = wsrc[3];
  }

  for (int k0 = 0; k0 < ND; k0 += 64) {
    {  // convert + write staged A (fp32 regs -> fp16 LDS)
      half8 h0, h1;
      h0[0] = (_Float16)pf0.x; h0[1] = (_Float16)pf0.y; h0[2] = (_Float16)pf0.z; h0[3] = (_Float16)pf0.w;
      h0[4] = (_Float16)pf1.x; h0[5] = (_Float16)pf1.y; h0[6] = (_Float16)pf1.z; h0[7] = (_Float16)pf1.w;
      h1[0] = (_Float16)pf2.x; h1[1] = (_Float16)pf2.y; h1[2] = (_Float16)pf2.z; h1[3] = (_Float16)pf2.w;
      h1[4] = (_Float16)pf3.x; h1[5] = (_Float16)pf3.y; h1[6] = (_Float16)pf3.z; h1[7] = (_Float16)pf3.w;
      *(half8*)&Asb[sr * 72 + sc] = h0;
      *(half8*)&Asb[sr * 72 + sc + 8] = h1;
      *(half8*)&Wsb[sr2 * 72 + sc2] = pw0;
      *(half8*)&Wsb[sr2 * 72 + sc2 + 8] = pw1;
      *(half8*)&Wsb[sr2 * 72 + sc2 + 16] = pw2;
      *(half8*)&Wsb[sr2 * 72 + sc2 + 24] = pw3;
    }
    __syncthreads();
    if (k0 + 64 < ND) {  // issue-early next k-step: overlaps MFMA below
      const float4* src =
          (const float4*)(A + (size_t)(row0 + sr) * ND + k0 + 64 + sc);
      pf0 = src[0]; pf1 = src[1]; pf2 = src[2]; pf3 = src[3];
      const half8* wsrc =
          (const half8*)(Wz + (size_t)(col0 + sr2) * ND + k0 + 64 + sc2);
      pw0 = wsrc[0]; pw1 = wsrc[1]; pw2 = wsrc[2]; pw3 = wsrc[3];
    }
#pragma unroll
    for (int ks = 0; ks < 2; ks++) {
      half8 a = *(const half8*)&Asb[(w * 16 + lrow) * 72 + ks * 32 + quad * 8];
#pragma unroll
      for (int nt = 0; nt < 8; nt++) {
        half8 b = *(const half8*)&Wsb[(nt * 16 + lrow) * 72 + ks * 32 + quad * 8];
        acc[nt] = __builtin_amdgcn_mfma_f32_16x16x32_f16(a, b, acc[nt], 0, 0, 0);
      }
    }
    __syncthreads();
  }

  const int tr0 = row0 & 1023;
  const int hh0 = col0 >> 6;  // even

  if (z <= 1) {
    // bounce via pool reused as [64][136] for coalesced half8 stores
#pragma unroll
    for (int nt = 0; nt < 8; nt++)
#pragma unroll
      for (int r = 0; r < 4; r++)
        pool[(w * 16 + quad * 4 + r) * 136 + nt * 16 + lrow] = (_Float16)acc[nt][r];
    __syncthreads();
    const int sce = (t & 3) * 32;
    _Float16* base = (z == 0) ? Qh : Kh;
    _Float16* dst = base + (size_t)(bb * NH + hh0 + (sce >> 6)) * NTQ * NDH +
                    (size_t)(tr0 + sr) * NDH + (sce & 63);
#pragma unroll
    for (int j = 0; j < 4; j++)
      *(half8*)(dst + 8 * j) = *(const half8*)&pool[sr * 136 + sce + 8 * j];
  } else {
    // V: bounce transposed via Wsb region [128][72] -> Vth[b][h][d][m]
#pragma unroll
    for (int nt = 0; nt < 8; nt++)
#pragma unroll
      for (int r = 0; r < 4; r++)
        Wsb[(nt * 16 + lrow) * 72 + w * 16 + quad * 4 + r] = (_Float16)acc[nt][r];
    __syncthreads();
    _Float16* dst = Vth +
        ((size_t)(bb * NH + hh0 + (sr2 >> 6)) * NDH + (sr2 & 63)) * NTM + tr0 + sc2;
#pragma unroll
    for (int j = 0; j < 4; j++)
      *(half8*)(dst + 8 * j) = *(const half8*)&Wsb[sr2 * 72 + sc2 + 8 * j];
  }
}

// ---------------------------------------------------------------------------
// Attention — byte-identical to round 4 (best verified attn).
// ---------------------------------------------------------------------------
__global__ __launch_bounds__(256) void attn_kernel(
    const _Float16* __restrict__ Qh, const _Float16* __restrict__ Kh,
    const _Float16* __restrict__ Vth, const int* __restrict__ mem_len,
    const int* __restrict__ qry_len, float* __restrict__ ctx_out,
    float* __restrict__ align_out) {
  const int bh = blockIdx.x;  // 0..63
  const int qt = blockIdx.y;  // 0..15
  const int bb = bh >> 3;
  const int hh = bh & 7;
  const int q0 = qt * 64;

  __shared__ __align__(16) _Float16 Ks[64][72];
  __shared__ __align__(16) _Float16 Vts[64][72];   // [d][m_local]
  __shared__ __align__(16) _Float16 Ps[4][16][72]; // per-wave P (A-layout src)
  __shared__ float vsum_lds[64];

  const int t = threadIdx.x, w = t >> 6, L = t & 63;
  const int lrow = L & 15, quad = L >> 4;
  const int qlen = qry_len[bb], mlen = mem_len[bb];
  const int mtop = (mlen + 63) >> 6;
  const bool has_causal = q0 < qlen;          // block-uniform
  const bool has_uniform = (q0 + 64) > qlen;  // block-uniform
  const int n_comp = has_causal ? min(qt + 1, mtop) : 0;
  const _Float16* Qbase = Qh + (size_t)bh * NTQ * NDH;
  const _Float16* Kbase = Kh + (size_t)bh * NTM * NDH;
  const _Float16* Vbase = Vth + (size_t)bh * NDH * NTM;
  const int sr = t >> 2, sc = (t & 3) * 16;
  const f32x4 zf = {0.f, 0.f, 0.f, 0.f};
  float* abase = align_out + (size_t)bh * NTQ * NTM;
  float* cbase = ctx_out + (size_t)bb * NTQ * NATTN + (size_t)hh * NDH;

  if (has_causal) {
    // ---- zero-fill skipped alignment columns for causal rows only ----
    if (n_comp < 16) {
      const int c0 = n_comp * 64;
      const int row = q0 + sr;
      if (row < qlen) {
        float* rp = abase + (size_t)row * NTM;
        const float4 z4 = {0.f, 0.f, 0.f, 0.f};
        for (int c = c0 + (t & 3) * 4; c < NTM; c += 16) *(float4*)(rp + c) = z4;
      }
    }
    // ---- Q fragments in registers (wave-private rows) ----
    const int qrow = q0 + w * 16 + lrow;
    const half8 qa0 = *(const half8*)(Qbase + (size_t)qrow * NDH + quad * 8);
    const half8 qa1 = *(const half8*)(Qbase + (size_t)qrow * NDH + 32 + quad * 8);
    const int qg = q0 + w * 16 + quad * 4;  // + r = global q row
    float rowsum[4] = {0.f, 0.f, 0.f, 0.f};

    // ---- pass 1: denominators (prefetched K staging) ----
    half8 kr0, kr1;
    {
      const half8* src = (const half8*)(Kbase + (size_t)sr * NDH + sc);
      kr0 = src[0]; kr1 = src[1];
    }
    for (int mt = 0; mt < n_comp; mt++) {
      *(half8*)&Ks[sr][sc] = kr0;
      *(half8*)&Ks[sr][sc + 8] = kr1;
      __syncthreads();
      if (mt + 1 < n_comp) {  // issue-early: overlaps the compute below
        const half8* src =
            (const half8*)(Kbase + (size_t)((mt + 1) * 64 + sr) * NDH + sc);
        kr0 = src[0]; kr1 = src[1];
      }
      f32x4 sacc[4];
#pragma unroll
      for (int i = 0; i < 4; i++) sacc[i] = zf;
#pragma unroll
      for (int nt = 0; nt < 4; nt++) {
        half8 b0 = *(const half8*)&Ks[nt * 16 + lrow][quad * 8];
        half8 b1 = *(const half8*)&Ks[nt * 16 + lrow][32 + quad * 8];
        sacc[nt] = __builtin_amdgcn_mfma_f32_16x16x32_f16(qa0, b0, sacc[nt], 0, 0, 0);
        sacc[nt] = __builtin_amdgcn_mfma_f32_16x16x32_f16(qa1, b1, sacc[nt], 0, 0, 0);
      }
#pragma unroll
      for (int nt = 0; nt < 4; nt++) {
        int m = mt * 64 + nt * 16 + lrow;
#pragma unroll
        for (int r = 0; r < 4; r++) {
          int q = qg + r;
          float p;
          if (q >= qlen) p = 0.0f;               // uniform row: handled later
          else if (m > q || m >= mlen) p = 0.0f; // masked
          else p = __expf(sacc[nt][r] * 0.125f);
          rowsum[r] += p;
        }
      }
      __syncthreads();
    }
    float inv[4];
#pragma unroll
    for (int r = 0; r < 4; r++) {
      float s = rowsum[r];
      s += __shfl_xor(s, 1, 16);
      s += __shfl_xor(s, 2, 16);
      s += __shfl_xor(s, 4, 16);
      s += __shfl_xor(s, 8, 16);
      inv[r] = 1.0f / s;  // inf for uniform rows; never used
    }

    // ---- pass 2: alignments + contexts (prefetched K+V staging) ----
    f32x4 cacc[4];
#pragma unroll
    for (int i = 0; i < 4; i++) cacc[i] = zf;

    half8 vr0, vr1;
    {
      const half8* ksrc = (const half8*)(Kbase + (size_t)sr * NDH + sc);
      kr0 = ksrc[0]; kr1 = ksrc[1];
      const half8* vsrc = (const half8*)(Vbase + (size_t)sr * NTM + sc);
      vr0 = vsrc[0]; vr1 = vsrc[1];
    }
    for (int mt = 0; mt < n_comp; mt++) {
      *(half8*)&Ks[sr][sc] = kr0;
      *(half8*)&Ks[sr][sc + 8] = kr1;
      *(half8*)&Vts[sr][sc] = vr0;
      *(half8*)&Vts[sr][sc + 8] = vr1;
      __syncthreads();
      if (mt + 1 < n_comp) {  // issue-early: overlaps the compute below
        const half8* ksrc =
            (const half8*)(Kbase + (size_t)((mt + 1) * 64 + sr) * NDH + sc);
        kr0 = ksrc[0]; kr1 = ksrc[1];
        const half8* vsrc =
            (const half8*)(Vbase + (size_t)sr * NTM + (mt + 1) * 64 + sc);
        vr0 = vsrc[0]; vr1 = vsrc[1];
      }
      f32x4 sacc[4];
#pragma unroll
      for (int i = 0; i < 4; i++) sacc[i] = zf;
#pragma unroll
      for (int nt = 0; nt < 4; nt++) {
        half8 b0 = *(const half8*)&Ks[nt * 16 + lrow][quad * 8];
        half8 b1 = *(const half8*)&Ks[nt * 16 + lrow][32 + quad * 8];
        sacc[nt] = __builtin_amdgcn_mfma_f32_16x16x32_f16(qa0, b0, sacc[nt], 0, 0, 0);
        sacc[nt] = __builtin_amdgcn_mfma_f32_16x16x32_f16(qa1, b1, sacc[nt], 0, 0, 0);
      }
#pragma unroll
      for (int nt = 0; nt < 4; nt++) {
        int m = mt * 64 + nt * 16 + lrow;
#pragma unroll
        for (int r = 0; r < 4; r++) {
          int q = qg + r;
          float p;
          if (q >= qlen) p = 0.0f;               // uniform row: handled later
          else if (m > q || m >= mlen) p = 0.0f;
          else p = __expf(sacc[nt][r] * 0.125f) * inv[r];
          if (q < qlen) abase[(size_t)q * NTM + m] = p;
          Ps[w][quad * 4 + r][nt * 16 + lrow] = (_Float16)p;
        }
      }
      // P @ V  (Ps is per-wave; in-wave DS ordering suffices, no barrier)
#pragma unroll
      for (int ks = 0; ks < 2; ks++) {
        half8 a = *(const half8*)&Ps[w][lrow][ks * 32 + quad * 8];
#pragma unroll
        for (int dt = 0; dt < 4; dt++) {
          half8 b = *(const half8*)&Vts[dt * 16 + lrow][ks * 32 + quad * 8];
          cacc[dt] = __builtin_amdgcn_mfma_f32_16x16x32_f16(a, b, cacc[dt], 0, 0, 0);
        }
      }
      __syncthreads();
    }

#pragma unroll
    for (int dt = 0; dt < 4; dt++) {
#pragma unroll
      for (int r = 0; r < 4; r++) {
        int q = qg + r;
        if (q < qlen) cbase[(size_t)q * NATTN + dt * 16 + lrow] = cacc[dt][r];
      }
    }
  }

  // ---- uniform rows: alignments = 1/1024 exactly; ctx = mean of V ----
  if (has_uniform) {
    const int d = t >> 2;   // 0..63
    const int seg = t & 3;  // 256-col segment
    const _Float16* vp = Vbase + (size_t)d * NTM + seg * 256;
    float s = 0.f;
#pragma unroll
    for (int j = 0; j < 32; j++) {
      half8 v = *(const half8*)(vp + 8 * j);
#pragma unroll
      for (int e = 0; e < 8; e++) s += (float)v[e];
    }
    s += __shfl_xor(s, 1, 4);
    s += __shfl_xor(s, 2, 4);
    if (seg == 0) vsum_lds[d] = s * (1.0f / 1024.0f);
    __syncthreads();
    const int qu0 = (q0 > qlen) ? q0 : qlen;
    for (int q = qu0 + w; q < q0 + 64; q += 4)
      cbase[(size_t)q * NATTN + L] = vsum_lds[L];
    const float cval = 1.0f / 1024.0f;  // exact (2^-10), matches ref softmax
    const f32x4 c4 = {cval, cval, cval, cval};
    for (int q = qu0 + w; q < q0 + 64; q += 4) {
      float* rp = abase + (size_t)q * NTM + L * 4;
#pragma unroll
      for (int j = 0; j < 4; j++) *(f32x4*)(rp + j * 256) = c4;
    }
  }
}

extern "C" void kernel_launch(void* const* d_in, const int* in_sizes, int n_in,
                              void* d_out, int out_size, void* d_ws,
                              size_t ws_size, hipStream_t stream) {
  const float* inputs = (const float*)d_in[0];
  const float* memory = (const float*)d_in[1];
  const float* Wq = (const float*)d_in[2];
  const float* Wk = (const float*)d_in[3];
  const float* Wv = (const float*)d_in[4];
  const int* mlen = (const int*)d_in[5];
  const int* qlen = (const int*)d_in[6];

  float* ctx = (float*)d_out;                     // (B,TQ,ATTN)
  float* align = ctx + (size_t)NB * NTQ * NATTN;  // (B,H,TQ,TM)

  _Float16* Qh = (_Float16*)d_ws;                    // 8 MB
  _Float16* Kh = Qh + (size_t)NB * NH * NTQ * NDH;   // 8 MB
  _Float16* Vth = Kh + (size_t)NB * NH * NTM * NDH;  // 8 MB
  // Wt (1.5 MB fp16) parked at the head of the alignments buffer: read only
  // by proj_kernel, fully overwritten by attn_kernel later in stream order.
  _Float16* Wt = (_Float16*)align;

  wprep_kernel<<<dim3(8, 8, 3), 256, 0, stream>>>(Wq, Wk, Wv, Wt);
  proj_kernel<<<dim3(1536), 256, 0, stream>>>(inputs, memory, Wt, mlen, qlen,
                                              Qh, Kh, Vth);
  attn_kernel<<<dim3(64, 16), 256, 0, stream>>>(Qh, Kh, Vth, mlen, qlen, ctx,
                                                align);
}